// Round 1
// baseline (568.080 us; speedup 1.0000x reference)
//
#include <hip/hip_runtime.h>
#include <hip/hip_bf16.h>
#include <cmath>

#define HID 128
#define NHEAD 2
#define CPH 64
#define ATT_SLOPE 0.2f
#define OUT_SLOPE 0.01f

// ---------------------------------------------------------------- weights prep
// BT[k][j] for j in [0,256): j<128 -> w_l[j][k], else w_r[j-128][k]
__global__ void prep_weights(const float* __restrict__ wl,
                             const float* __restrict__ wr,
                             float* __restrict__ BT) {
    int idx = blockIdx.x * blockDim.x + threadIdx.x;   // over 128*128
    if (idx < HID * HID) {
        int j = idx >> 7;      // out row
        int k = idx & 127;     // in col
        BT[k * 256 + j]       = wl[idx];
        BT[k * 256 + 128 + j] = wr[idx];
    }
}

// ---------------------------------------------------------------- CSR build
__global__ void count_deg(const int* __restrict__ dst, int* __restrict__ deg, int E) {
    int e = blockIdx.x * blockDim.x + threadIdx.x;
    if (e < E) atomicAdd(&deg[dst[e]], 1);
}

// single-block scan (1024 threads): offsets = exclusive_scan(deg); cursor = copy
__global__ __launch_bounds__(1024) void scan_offsets(const int* __restrict__ deg,
                                                     int* __restrict__ offsets,
                                                     int* __restrict__ cursor, int n) {
    __shared__ int wtot[16];
    __shared__ int wbase[16];
    __shared__ int chunk_tot;
    __shared__ int base_s;
    int t = threadIdx.x, lane = t & 63, wid = t >> 6;
    if (t == 0) base_s = 0;
    __syncthreads();
    for (int base = 0; base < n; base += 1024) {
        int i = base + t;
        int v = (i < n) ? deg[i] : 0;
        int incl = v;
        #pragma unroll
        for (int off = 1; off < 64; off <<= 1) {
            int u = __shfl_up(incl, off, 64);
            if (lane >= off) incl += u;
        }
        if (lane == 63) wtot[wid] = incl;
        __syncthreads();
        if (t < 16) {
            int wv = wtot[t];
            int wincl = wv;
            #pragma unroll
            for (int off = 1; off < 16; off <<= 1) {
                int u = __shfl_up(wincl, off, 64);
                if (t >= off) wincl += u;
            }
            wbase[t] = wincl - wv;        // exclusive wave base
            if (t == 15) chunk_tot = wincl;
        }
        __syncthreads();
        int excl = base_s + wbase[wid] + (incl - v);
        if (i < n) { offsets[i] = excl; cursor[i] = excl; }
        __syncthreads();
        if (t == 0) base_s += chunk_tot;
        __syncthreads();
    }
    if (t == 0) offsets[n] = base_s;
}

__global__ void fill_csr(const int* __restrict__ src, const int* __restrict__ dst,
                         int* __restrict__ cursor, int* __restrict__ csr_src, int E) {
    int e = blockIdx.x * blockDim.x + threadIdx.x;
    if (e < E) {
        int d = dst[e];
        int p = atomicAdd(&cursor[d], 1);
        csr_src[p] = src[e];
    }
}

// ---------------------------------------------------------------- fused GEMM
// X [n,128] fp32 @ BT [128,256] -> xl [n,128], xr [n,128]
#define GN 32   // nodes per block
__global__ __launch_bounds__(256) void gemm_xlxr(const float* __restrict__ X,
                                                 const float* __restrict__ BT,
                                                 float* __restrict__ xl,
                                                 float* __restrict__ xr, int nNodes) {
    __shared__ float xs[GN][HID];
    int n0 = blockIdx.x * GN;
    int t = threadIdx.x;
    const float4* Xv = (const float4*)X;
    // stage X tile: GN*32 = 1024 float4 slots, 256 threads x 4
    #pragma unroll
    for (int r = 0; r < 4; ++r) {
        int idx = t + r * 256;
        int i = idx >> 5, kk = idx & 31;
        float4 v = make_float4(0.f, 0.f, 0.f, 0.f);
        if (n0 + i < nNodes) v = Xv[(size_t)(n0 + i) * 32 + kk];
        *((float4*)&xs[i][kk * 4]) = v;
    }
    __syncthreads();
    int j = t;   // output column 0..255
    float acc[GN];
    #pragma unroll
    for (int i = 0; i < GN; ++i) acc[i] = 0.f;
    for (int k4 = 0; k4 < 32; ++k4) {
        float w0 = BT[(k4 * 4 + 0) * 256 + j];
        float w1 = BT[(k4 * 4 + 1) * 256 + j];
        float w2 = BT[(k4 * 4 + 2) * 256 + j];
        float w3 = BT[(k4 * 4 + 3) * 256 + j];
        #pragma unroll
        for (int i = 0; i < GN; ++i) {
            float4 xv = *((const float4*)&xs[i][k4 * 4]);
            acc[i] += xv.x * w0;
            acc[i] += xv.y * w1;
            acc[i] += xv.z * w2;
            acc[i] += xv.w * w3;
        }
    }
    float* dstp = (j < 128) ? xl : xr;
    int jj = j & 127;
    #pragma unroll
    for (int i = 0; i < GN; ++i) {
        int n = n0 + i;
        if (n < nNodes) dstp[(size_t)n * HID + jj] = acc[i];
    }
}

// ---------------------------------------------------------------- fused attention
// one wave per node; lane = channel (C=64); online softmax over incoming edges
template <int LAYER>
__global__ __launch_bounds__(256) void gat_edge(const float* __restrict__ xl,
                                                const float* __restrict__ xr,
                                                const int* __restrict__ offsets,
                                                const int* __restrict__ csr_src,
                                                const float* __restrict__ att,
                                                const float* __restrict__ bias,
                                                const float* __restrict__ h1,
                                                float* __restrict__ outp, int nNodes) {
    int wave = (int)((blockIdx.x * blockDim.x + threadIdx.x) >> 6);
    int lane = threadIdx.x & 63;
    if (wave >= nNodes) return;
    int n = wave;
    float a0 = att[lane];
    float a1 = att[64 + lane];
    float xr0 = xr[(size_t)n * HID + lane];
    float xr1 = xr[(size_t)n * HID + 64 + lane];
    int e0 = offsets[n], e1 = offsets[n + 1];
    float m0 = -INFINITY, m1 = -INFINITY;
    float l0 = 0.f, l1 = 0.f, acc0 = 0.f, acc1 = 0.f;
    for (int e = e0; e < e1; ++e) {
        int s = csr_src[e];
        float xl0 = xl[(size_t)s * HID + lane];
        float xl1 = xl[(size_t)s * HID + 64 + lane];
        float t0 = xl0 + xr0; t0 = t0 > 0.f ? t0 : ATT_SLOPE * t0;
        float t1 = xl1 + xr1; t1 = t1 > 0.f ? t1 : ATT_SLOPE * t1;
        float p0 = t0 * a0, p1 = t1 * a1;
        #pragma unroll
        for (int off = 32; off > 0; off >>= 1) {
            p0 += __shfl_xor(p0, off, 64);
            p1 += __shfl_xor(p1, off, 64);
        }
        // p0/p1 = per-head attention logits, uniform across lanes
        float nm0 = fmaxf(m0, p0);
        float s0 = __expf(m0 - nm0);   // exp(-inf)=0 on first edge
        float w0 = __expf(p0 - nm0);
        l0 = l0 * s0 + w0;
        acc0 = acc0 * s0 + w0 * xl0;
        m0 = nm0;
        float nm1 = fmaxf(m1, p1);
        float s1 = __expf(m1 - nm1);
        float w1 = __expf(p1 - nm1);
        l1 = l1 * s1 + w1;
        acc1 = acc1 * s1 + w1 * xl1;
        m1 = nm1;
    }
    float o0 = acc0 / (l0 + 1e-16f) + bias[lane];
    float o1 = acc1 / (l1 + 1e-16f) + bias[64 + lane];
    if (LAYER == 1) {
        o0 = o0 > 0.f ? o0 : OUT_SLOPE * o0;
        o1 = o1 > 0.f ? o1 : OUT_SLOPE * o1;
        outp[(size_t)n * HID + lane] = o0;
        outp[(size_t)n * HID + 64 + lane] = o1;
    } else {
        outp[(size_t)n * HID + lane]      = h1[(size_t)n * HID + lane] + o0;
        outp[(size_t)n * HID + 64 + lane] = h1[(size_t)n * HID + 64 + lane] + o1;
    }
}

// ---------------------------------------------------------------- launch
extern "C" void kernel_launch(void* const* d_in, const int* in_sizes, int n_in,
                              void* d_out, int out_size, void* d_ws, size_t ws_size,
                              hipStream_t stream) {
    const float* x    = (const float*)d_in[0];
    const int* ei     = (const int*)d_in[1];
    const float* w_l1 = (const float*)d_in[2];
    const float* w_r1 = (const float*)d_in[3];
    const float* att1 = (const float*)d_in[4];
    const float* b1   = (const float*)d_in[5];
    const float* w_l2 = (const float*)d_in[6];
    const float* w_r2 = (const float*)d_in[7];
    const float* att2 = (const float*)d_in[8];
    const float* b2   = (const float*)d_in[9];

    const int N = in_sizes[0] / HID;
    const int E = in_sizes[1] / 2;
    const int* srcp = ei;
    const int* dstp = ei + E;

    // workspace layout
    int* deg      = (int*)d_ws;                  // N
    int* offsets  = deg + N;                     // N+1
    int* cursor   = offsets + (N + 1);           // N
    int* csr_src  = cursor + N;                  // E
    float* BT     = (float*)(csr_src + E);       // 128*256
    float* xlbuf  = BT + 128 * 256;              // N*128
    float* xrbuf  = xlbuf + (size_t)N * HID;     // N*128
    float* h1buf  = xrbuf + (size_t)N * HID;     // N*128
    float* outf   = (float*)d_out;

    const int eb = (E + 255) / 256;
    const int gb = (N + GN - 1) / GN;
    const int ab = (N + 3) / 4;     // 4 waves (nodes) per 256-thread block

    // CSR (shared by both layers)
    hipMemsetAsync(deg, 0, (size_t)N * sizeof(int), stream);
    count_deg<<<eb, 256, 0, stream>>>(dstp, deg, E);
    scan_offsets<<<1, 1024, 0, stream>>>(deg, offsets, cursor, N);
    fill_csr<<<eb, 256, 0, stream>>>(srcp, dstp, cursor, csr_src, E);

    // layer 1
    prep_weights<<<64, 256, 0, stream>>>(w_l1, w_r1, BT);
    gemm_xlxr<<<gb, 256, 0, stream>>>(x, BT, xlbuf, xrbuf, N);
    gat_edge<1><<<ab, 256, 0, stream>>>(xlbuf, xrbuf, offsets, csr_src, att1, b1,
                                        nullptr, h1buf, N);
    // layer 2
    prep_weights<<<64, 256, 0, stream>>>(w_l2, w_r2, BT);
    gemm_xlxr<<<gb, 256, 0, stream>>>(h1buf, BT, xlbuf, xrbuf, N);
    gat_edge<2><<<ab, 256, 0, stream>>>(xlbuf, xrbuf, offsets, csr_src, att2, b2,
                                        h1buf, outf, N);
}

// Round 2
// 373.288 us; speedup vs baseline: 1.5218x; 1.5218x over previous
//
#include <hip/hip_runtime.h>
#include <hip/hip_bf16.h>
#include <cmath>

#define HID 128
#define ATT_SLOPE 0.2f
#define OUT_SLOPE 0.01f

// ---------------------------------------------------------------- weights prep
// BT[k][j] for j in [0,256): j<128 -> w_l[j][k], else w_r[j-128][k]
__global__ void prep_weights(const float* __restrict__ wl,
                             const float* __restrict__ wr,
                             float* __restrict__ BT) {
    int idx = blockIdx.x * blockDim.x + threadIdx.x;   // over 128*128
    if (idx < HID * HID) {
        int j = idx >> 7;      // out row
        int k = idx & 127;     // in col
        BT[k * 256 + j]       = wl[idx];
        BT[k * 256 + 128 + j] = wr[idx];
    }
}

// ---------------------------------------------------------------- CSR build
__global__ void count_deg(const int* __restrict__ dst, int* __restrict__ deg, int E) {
    int e = blockIdx.x * blockDim.x + threadIdx.x;
    if (e < E) atomicAdd(&deg[dst[e]], 1);
}

// phase 1: per-block sums (64 blocks x 1024 threads, chunk=ch<=1024)
__global__ __launch_bounds__(1024) void scan_part(const int* __restrict__ deg,
                                                  int* __restrict__ bsum, int N, int ch) {
    int b = blockIdx.x, t = threadIdx.x;
    int lane = t & 63, wid = t >> 6;
    int i = b * ch + t;
    int v = (t < ch && i < N) ? deg[i] : 0;
    #pragma unroll
    for (int off = 32; off > 0; off >>= 1) v += __shfl_xor(v, off, 64);
    __shared__ int ws[16];
    if (lane == 0) ws[wid] = v;
    __syncthreads();
    if (t == 0) {
        int s = 0;
        #pragma unroll
        for (int k = 0; k < 16; ++k) s += ws[k];
        bsum[b] = s;
    }
}

// phase 2: exclusive scan of 64 block sums (1 block, 64 threads)
__global__ void scan_base(const int* __restrict__ bsum, int* __restrict__ bbase, int nb) {
    int t = threadIdx.x;
    int v = (t < nb) ? bsum[t] : 0;
    int incl = v;
    #pragma unroll
    for (int off = 1; off < 64; off <<= 1) {
        int u = __shfl_up(incl, off, 64);
        if (t >= off) incl += u;
    }
    if (t < nb) bbase[t] = incl - v;
}

// phase 3: local exclusive scan + block base
__global__ __launch_bounds__(1024) void scan_final(const int* __restrict__ deg,
                                                   const int* __restrict__ bbase,
                                                   int* __restrict__ offsets,
                                                   int* __restrict__ cursor,
                                                   int N, int E, int ch) {
    int b = blockIdx.x, t = threadIdx.x, lane = t & 63, wid = t >> 6;
    int i = b * ch + t;
    int v = (t < ch && i < N) ? deg[i] : 0;
    int incl = v;
    #pragma unroll
    for (int off = 1; off < 64; off <<= 1) {
        int u = __shfl_up(incl, off, 64);
        if (lane >= off) incl += u;
    }
    __shared__ int wtot[16], wbase[16];
    if (lane == 63) wtot[wid] = incl;
    __syncthreads();
    if (t < 16) {
        int wv = wtot[t];
        int wincl = wv;
        #pragma unroll
        for (int off = 1; off < 16; off <<= 1) {
            int u = __shfl_up(wincl, off, 64);
            if (t >= off) wincl += u;
        }
        wbase[t] = wincl - wv;
    }
    __syncthreads();
    int excl = bbase[b] + wbase[wid] + (incl - v);
    if (t < ch && i < N) { offsets[i] = excl; cursor[i] = excl; }
    if (b == 0 && t == 0) offsets[N] = E;
}

__global__ void fill_csr(const int* __restrict__ src, const int* __restrict__ dst,
                         int* __restrict__ cursor, int* __restrict__ csr_src, int E) {
    int e = blockIdx.x * blockDim.x + threadIdx.x;
    if (e < E) {
        int d = dst[e];
        int p = atomicAdd(&cursor[d], 1);
        csr_src[p] = src[e];
    }
}

// ---------------------------------------------------------------- GEMM
// X [n,128] @ BT [128,256] -> xl [n,128], xr [n,128]
// block: 64 rows x 256 cols; thread: 16 rows x 4 cols -> LDS:VALU = 192:512 cyc
#define GM 64
__global__ __launch_bounds__(256) void gemm_xlxr(const float* __restrict__ X,
                                                 const float* __restrict__ BT,
                                                 float* __restrict__ xl,
                                                 float* __restrict__ xr, int nNodes) {
    __shared__ float xs[GM][HID];   // 32 KB
    int n0 = blockIdx.x * GM;
    int t = threadIdx.x;
    const float4* Xv = (const float4*)X;
    #pragma unroll
    for (int r = 0; r < 8; ++r) {
        int idx = t + r * 256;
        int i = idx >> 5, kk = idx & 31;
        float4 v = make_float4(0.f, 0.f, 0.f, 0.f);
        if (n0 + i < nNodes) v = Xv[(size_t)(n0 + i) * 32 + kk];
        *((float4*)&xs[i][kk * 4]) = v;
    }
    __syncthreads();
    int tj = t & 63;          // col quad: cols 4*tj .. 4*tj+3
    int ti = t >> 6;          // row group: rows ti*16 .. ti*16+15
    float acc[16][4];
    #pragma unroll
    for (int r = 0; r < 16; ++r)
        #pragma unroll
        for (int c = 0; c < 4; ++c) acc[r][c] = 0.f;
    const float4* BTv = (const float4*)BT;
    for (int k4 = 0; k4 < 32; ++k4) {
        float4 w0 = BTv[(k4 * 4 + 0) * 64 + tj];
        float4 w1 = BTv[(k4 * 4 + 1) * 64 + tj];
        float4 w2 = BTv[(k4 * 4 + 2) * 64 + tj];
        float4 w3 = BTv[(k4 * 4 + 3) * 64 + tj];
        #pragma unroll
        for (int r = 0; r < 16; ++r) {
            float4 xv = *((const float4*)&xs[ti * 16 + r][k4 * 4]);
            acc[r][0] = fmaf(xv.x, w0.x, acc[r][0]);
            acc[r][0] = fmaf(xv.y, w1.x, acc[r][0]);
            acc[r][0] = fmaf(xv.z, w2.x, acc[r][0]);
            acc[r][0] = fmaf(xv.w, w3.x, acc[r][0]);
            acc[r][1] = fmaf(xv.x, w0.y, acc[r][1]);
            acc[r][1] = fmaf(xv.y, w1.y, acc[r][1]);
            acc[r][1] = fmaf(xv.z, w2.y, acc[r][1]);
            acc[r][1] = fmaf(xv.w, w3.y, acc[r][1]);
            acc[r][2] = fmaf(xv.x, w0.z, acc[r][2]);
            acc[r][2] = fmaf(xv.y, w1.z, acc[r][2]);
            acc[r][2] = fmaf(xv.z, w2.z, acc[r][2]);
            acc[r][2] = fmaf(xv.w, w3.z, acc[r][2]);
            acc[r][3] = fmaf(xv.x, w0.w, acc[r][3]);
            acc[r][3] = fmaf(xv.y, w1.w, acc[r][3]);
            acc[r][3] = fmaf(xv.z, w2.w, acc[r][3]);
            acc[r][3] = fmaf(xv.w, w3.w, acc[r][3]);
        }
    }
    float* dstp = (tj < 32) ? xl : xr;
    int jj = (tj * 4) & 127;
    #pragma unroll
    for (int r = 0; r < 16; ++r) {
        int n = n0 + ti * 16 + r;
        if (n < nNodes)
            *((float4*)&dstp[(size_t)n * HID + jj]) =
                make_float4(acc[r][0], acc[r][1], acc[r][2], acc[r][3]);
    }
}

// ---------------------------------------------------------------- fused attention
// one wave per node; lanes 0-31 = head0 (channels hl, hl+32), lanes 32-63 = head1.
// per-edge logit reduction = 5 xor-shuffles within each 32-half; 4-edge unroll
// with a single online-softmax rescale per group.
__device__ __forceinline__ float hred32(float p) {
    p += __shfl_xor(p, 16, 32);
    p += __shfl_xor(p, 8, 32);
    p += __shfl_xor(p, 4, 32);
    p += __shfl_xor(p, 2, 32);
    p += __shfl_xor(p, 1, 32);
    return p;
}

__device__ __forceinline__ float edot(float xa, float xb, float xra, float xrb,
                                      float aa, float ab) {
    float ta = xa + xra; ta = ta > 0.f ? ta : ATT_SLOPE * ta;
    float tb = xb + xrb; tb = tb > 0.f ? tb : ATT_SLOPE * tb;
    return fmaf(ta, aa, tb * ab);
}

template <int LAYER>
__global__ __launch_bounds__(256) void gat_edge(const float* __restrict__ xl,
                                                const float* __restrict__ xr,
                                                const int* __restrict__ offsets,
                                                const int* __restrict__ csr_src,
                                                const float* __restrict__ att,
                                                const float* __restrict__ bias,
                                                const float* __restrict__ h1,
                                                float* __restrict__ outp, int nNodes) {
    int wave = (int)((blockIdx.x * blockDim.x + threadIdx.x) >> 6);
    int lane = threadIdx.x & 63;
    if (wave >= nNodes) return;
    int n = wave;
    int fo = (lane >> 5) * 64;   // head feature offset (0 or 64)
    int hl = lane & 31;          // channel within half
    int ca = fo + hl, cb = fo + hl + 32;
    float aa = att[ca], ab = att[cb];
    size_t nb = (size_t)n * HID;
    float xra = xr[nb + ca], xrb = xr[nb + cb];
    int e0 = offsets[n], e1 = offsets[n + 1];
    float m = -INFINITY, l = 0.f, acc_a = 0.f, acc_b = 0.f;
    int e = e0;
    for (; e + 4 <= e1; e += 4) {
        int s0 = csr_src[e + 0], s1 = csr_src[e + 1];
        int s2 = csr_src[e + 2], s3 = csr_src[e + 3];
        const float* r0 = xl + (size_t)s0 * HID + ca;
        const float* r1 = xl + (size_t)s1 * HID + ca;
        const float* r2 = xl + (size_t)s2 * HID + ca;
        const float* r3 = xl + (size_t)s3 * HID + ca;
        float xa0 = r0[0], xb0 = r0[32];
        float xa1 = r1[0], xb1 = r1[32];
        float xa2 = r2[0], xb2 = r2[32];
        float xa3 = r3[0], xb3 = r3[32];
        float p0 = edot(xa0, xb0, xra, xrb, aa, ab);
        float p1 = edot(xa1, xb1, xra, xrb, aa, ab);
        float p2 = edot(xa2, xb2, xra, xrb, aa, ab);
        float p3 = edot(xa3, xb3, xra, xrb, aa, ab);
        p0 = hred32(p0); p1 = hred32(p1); p2 = hred32(p2); p3 = hred32(p3);
        float nm = fmaxf(fmaxf(m, fmaxf(p0, p1)), fmaxf(p2, p3));
        float sc = __expf(m - nm);
        float w0 = __expf(p0 - nm), w1 = __expf(p1 - nm);
        float w2 = __expf(p2 - nm), w3 = __expf(p3 - nm);
        l = l * sc + ((w0 + w1) + (w2 + w3));
        acc_a = acc_a * sc + (fmaf(w0, xa0, w1 * xa1) + fmaf(w2, xa2, w3 * xa3));
        acc_b = acc_b * sc + (fmaf(w0, xb0, w1 * xb1) + fmaf(w2, xb2, w3 * xb3));
        m = nm;
    }
    for (; e < e1; ++e) {
        int s = csr_src[e];
        const float* r0 = xl + (size_t)s * HID + ca;
        float xa = r0[0], xb = r0[32];
        float p = edot(xa, xb, xra, xrb, aa, ab);
        p = hred32(p);
        float nm = fmaxf(m, p);
        float sc = __expf(m - nm);
        float w = __expf(p - nm);
        l = l * sc + w;
        acc_a = acc_a * sc + w * xa;
        acc_b = acc_b * sc + w * xb;
        m = nm;
    }
    float inv = 1.f / (l + 1e-16f);
    float oa = acc_a * inv + bias[ca];
    float ob = acc_b * inv + bias[cb];
    if (LAYER == 1) {
        oa = oa > 0.f ? oa : OUT_SLOPE * oa;
        ob = ob > 0.f ? ob : OUT_SLOPE * ob;
        outp[nb + ca] = oa;
        outp[nb + cb] = ob;
    } else {
        outp[nb + ca] = h1[nb + ca] + oa;
        outp[nb + cb] = h1[nb + cb] + ob;
    }
}

// ---------------------------------------------------------------- launch
extern "C" void kernel_launch(void* const* d_in, const int* in_sizes, int n_in,
                              void* d_out, int out_size, void* d_ws, size_t ws_size,
                              hipStream_t stream) {
    const float* x    = (const float*)d_in[0];
    const int* ei     = (const int*)d_in[1];
    const float* w_l1 = (const float*)d_in[2];
    const float* w_r1 = (const float*)d_in[3];
    const float* att1 = (const float*)d_in[4];
    const float* b1   = (const float*)d_in[5];
    const float* w_l2 = (const float*)d_in[6];
    const float* w_r2 = (const float*)d_in[7];
    const float* att2 = (const float*)d_in[8];
    const float* b2   = (const float*)d_in[9];

    const int N = in_sizes[0] / HID;
    const int E = in_sizes[1] / 2;
    const int* srcp = ei;
    const int* dstp = ei + E;

    // workspace layout: float4-aligned buffers first
    float* xlbuf  = (float*)d_ws;                    // N*128
    float* xrbuf  = xlbuf + (size_t)N * HID;         // N*128
    float* h1buf  = xrbuf + (size_t)N * HID;         // N*128
    float* BT     = h1buf + (size_t)N * HID;         // 128*256
    int* deg      = (int*)(BT + 128 * 256);          // N
    int* offsets  = deg + N;                         // N+1
    int* cursor   = offsets + (N + 1);               // N
    int* csr_src  = cursor + N;                      // E
    int* bsum     = csr_src + E;                     // 64
    int* bbase    = bsum + 64;                       // 64
    float* outf   = (float*)d_out;

    const int eb = (E + 255) / 256;
    const int gb = (N + GM - 1) / GM;
    const int ab = (N + 3) / 4;
    const int ch = (N + 63) / 64;    // per-block scan chunk (<=1024 for N<=65536)

    // CSR (shared by both layers)
    hipMemsetAsync(deg, 0, (size_t)N * sizeof(int), stream);
    count_deg<<<eb, 256, 0, stream>>>(dstp, deg, E);
    scan_part<<<64, 1024, 0, stream>>>(deg, bsum, N, ch);
    scan_base<<<1, 64, 0, stream>>>(bsum, bbase, 64);
    scan_final<<<64, 1024, 0, stream>>>(deg, bbase, offsets, cursor, N, E, ch);
    fill_csr<<<eb, 256, 0, stream>>>(srcp, dstp, cursor, csr_src, E);

    // layer 1
    prep_weights<<<64, 256, 0, stream>>>(w_l1, w_r1, BT);
    gemm_xlxr<<<gb, 256, 0, stream>>>(x, BT, xlbuf, xrbuf, N);
    gat_edge<1><<<ab, 256, 0, stream>>>(xlbuf, xrbuf, offsets, csr_src, att1, b1,
                                        nullptr, h1buf, N);
    // layer 2
    prep_weights<<<64, 256, 0, stream>>>(w_l2, w_r2, BT);
    gemm_xlxr<<<gb, 256, 0, stream>>>(h1buf, BT, xlbuf, xrbuf, N);
    gat_edge<2><<<ab, 256, 0, stream>>>(xlbuf, xrbuf, offsets, csr_src, att2, b2,
                                        h1buf, outf, N);
}

// Round 3
// 324.137 us; speedup vs baseline: 1.7526x; 1.1516x over previous
//
#include <hip/hip_runtime.h>
#include <hip/hip_bf16.h>
#include <cmath>

#define HID 128
#define ATT_SLOPE 0.2f
#define OUT_SLOPE 0.01f

typedef __attribute__((ext_vector_type(8))) short bf16x8;
typedef __attribute__((ext_vector_type(4))) float f32x4;

__device__ __forceinline__ short f2bf(float f) {
    __hip_bfloat16 h = __float2bfloat16(f);
    return *reinterpret_cast<short*>(&h);
}

// ---------------------------------------------------------------- CSR build
__global__ void count_deg(const int* __restrict__ dst, int* __restrict__ deg, int E) {
    int e = blockIdx.x * blockDim.x + threadIdx.x;
    if (e < E) atomicAdd(&deg[dst[e]], 1);
}

// phase 1: per-block sums (64 blocks x 1024 threads, chunk=ch<=1024)
__global__ __launch_bounds__(1024) void scan_part(const int* __restrict__ deg,
                                                  int* __restrict__ bsum, int N, int ch) {
    int b = blockIdx.x, t = threadIdx.x;
    int lane = t & 63, wid = t >> 6;
    int i = b * ch + t;
    int v = (t < ch && i < N) ? deg[i] : 0;
    #pragma unroll
    for (int off = 32; off > 0; off >>= 1) v += __shfl_xor(v, off, 64);
    __shared__ int ws[16];
    if (lane == 0) ws[wid] = v;
    __syncthreads();
    if (t == 0) {
        int s = 0;
        #pragma unroll
        for (int k = 0; k < 16; ++k) s += ws[k];
        bsum[b] = s;
    }
}

// phase 2: exclusive scan of 64 block sums (1 block, 64 threads)
__global__ void scan_base(const int* __restrict__ bsum, int* __restrict__ bbase, int nb) {
    int t = threadIdx.x;
    int v = (t < nb) ? bsum[t] : 0;
    int incl = v;
    #pragma unroll
    for (int off = 1; off < 64; off <<= 1) {
        int u = __shfl_up(incl, off, 64);
        if (t >= off) incl += u;
    }
    if (t < nb) bbase[t] = incl - v;
}

// phase 3: local exclusive scan + block base
__global__ __launch_bounds__(1024) void scan_final(const int* __restrict__ deg,
                                                   const int* __restrict__ bbase,
                                                   int* __restrict__ offsets,
                                                   int* __restrict__ cursor,
                                                   int N, int E, int ch) {
    int b = blockIdx.x, t = threadIdx.x, lane = t & 63, wid = t >> 6;
    int i = b * ch + t;
    int v = (t < ch && i < N) ? deg[i] : 0;
    int incl = v;
    #pragma unroll
    for (int off = 1; off < 64; off <<= 1) {
        int u = __shfl_up(incl, off, 64);
        if (lane >= off) incl += u;
    }
    __shared__ int wtot[16], wbase[16];
    if (lane == 63) wtot[wid] = incl;
    __syncthreads();
    if (t < 16) {
        int wv = wtot[t];
        int wincl = wv;
        #pragma unroll
        for (int off = 1; off < 16; off <<= 1) {
            int u = __shfl_up(wincl, off, 64);
            if (t >= off) wincl += u;
        }
        wbase[t] = wincl - wv;
    }
    __syncthreads();
    int excl = bbase[b] + wbase[wid] + (incl - v);
    if (t < ch && i < N) { offsets[i] = excl; cursor[i] = excl; }
    if (b == 0 && t == 0) offsets[N] = E;
}

__global__ void fill_csr(const int* __restrict__ src, const int* __restrict__ dst,
                         int* __restrict__ cursor, int* __restrict__ csr_src, int E) {
    int e = blockIdx.x * blockDim.x + threadIdx.x;
    if (e < E) {
        int d = dst[e];
        int p = atomicAdd(&cursor[d], 1);
        csr_src[p] = src[e];
    }
}

// ---------------------------------------------------------------- MFMA GEMM
// out[n][j] = sum_k X[n][k] * W[j][k],  j in [0,256): j<128 -> w_l -> xl,
// j>=128 -> w_r -> xr.  bf16 inputs, fp32 accumulate.
// Block: 64 rows x 256 cols. Wave w: cols w*64..w*64+63, all 64 rows.
// 16x16x32 MFMA; A[m=lane&15][k=quad*8+j], B[n=lane&15][k=quad*8+j],
// C: col=lane&15, row=quad*4+reg.
#define GM 64
#define ASTRIDE 144   // 128 + 16 bf16 pad: 288 B row stride, 16B-aligned
__global__ __launch_bounds__(256) void gemm_xlxr(const float* __restrict__ X,
                                                 const float* __restrict__ wl,
                                                 const float* __restrict__ wr,
                                                 float* __restrict__ xl,
                                                 float* __restrict__ xr, int nNodes) {
    __shared__ __align__(16) short as[GM][ASTRIDE];
    int n0 = blockIdx.x * GM;
    int t = threadIdx.x;
    int w = t >> 6, lane = t & 63;
    int q = lane >> 4, ln = lane & 15;

    // ---- stage A: 64 rows x 128 k fp32 -> bf16 LDS (each thread 4 chunks of 8)
    #pragma unroll
    for (int it = 0; it < 4; ++it) {
        int chunk = it * 256 + t;
        int r = chunk >> 4, c = chunk & 15;   // row, k-chunk (8 elements)
        int gr = n0 + r;
        float4 u = make_float4(0.f, 0.f, 0.f, 0.f);
        float4 v = make_float4(0.f, 0.f, 0.f, 0.f);
        if (gr < nNodes) {
            const float4* p = (const float4*)(X + (size_t)gr * HID + c * 8);
            u = p[0]; v = p[1];
        }
        bf16x8 b;
        b[0] = f2bf(u.x); b[1] = f2bf(u.y); b[2] = f2bf(u.z); b[3] = f2bf(u.w);
        b[4] = f2bf(v.x); b[5] = f2bf(v.y); b[6] = f2bf(v.z); b[7] = f2bf(v.w);
        *(bf16x8*)&as[r][c * 8] = b;
    }

    // ---- load B fragments straight from weights (L2-hot, 512 B/lane)
    bf16x8 bfrag[4][4];   // [ct][ks]
    #pragma unroll
    for (int ct = 0; ct < 4; ++ct) {
        int col = w * 64 + ct * 16 + ln;
        const float* Wp = (col < 128) ? (wl + (size_t)col * HID)
                                      : (wr + (size_t)(col - 128) * HID);
        #pragma unroll
        for (int ks = 0; ks < 4; ++ks) {
            const float4* p = (const float4*)(Wp + ks * 32 + q * 8);
            float4 u = p[0], v = p[1];
            bf16x8 b;
            b[0] = f2bf(u.x); b[1] = f2bf(u.y); b[2] = f2bf(u.z); b[3] = f2bf(u.w);
            b[4] = f2bf(v.x); b[5] = f2bf(v.y); b[6] = f2bf(v.z); b[7] = f2bf(v.w);
            bfrag[ct][ks] = b;
        }
    }
    __syncthreads();

    // ---- MFMA main: 4 row-tiles x 4 col-tiles x 4 k-steps
    f32x4 acc[4][4];   // [rt][ct]
    #pragma unroll
    for (int rt = 0; rt < 4; ++rt)
        #pragma unroll
        for (int ct = 0; ct < 4; ++ct) acc[rt][ct] = (f32x4){0.f, 0.f, 0.f, 0.f};

    #pragma unroll
    for (int rt = 0; rt < 4; ++rt) {
        bf16x8 afrag[4];
        #pragma unroll
        for (int ks = 0; ks < 4; ++ks)
            afrag[ks] = *(const bf16x8*)&as[rt * 16 + ln][ks * 32 + q * 8];
        #pragma unroll
        for (int ks = 0; ks < 4; ++ks)
            #pragma unroll
            for (int ct = 0; ct < 4; ++ct)
                acc[rt][ct] = __builtin_amdgcn_mfma_f32_16x16x32_bf16(
                    afrag[ks], bfrag[ct][ks], acc[rt][ct], 0, 0, 0);
    }

    // ---- store: C layout col=ln, row=q*4+i
    #pragma unroll
    for (int rt = 0; rt < 4; ++rt) {
        #pragma unroll
        for (int ct = 0; ct < 4; ++ct) {
            int col = w * 64 + ct * 16 + ln;
            float* dstp = (col < 128) ? xl : xr;
            int jj = col & 127;
            #pragma unroll
            for (int i = 0; i < 4; ++i) {
                int row = n0 + rt * 16 + q * 4 + i;
                if (row < nNodes) dstp[(size_t)row * HID + jj] = acc[rt][ct][i];
            }
        }
    }
}

// ---------------------------------------------------------------- fused attention
// one wave per node; lanes 0-31 = head0 (channels hl, hl+32), lanes 32-63 = head1.
__device__ __forceinline__ float hred32(float p) {
    p += __shfl_xor(p, 16, 32);
    p += __shfl_xor(p, 8, 32);
    p += __shfl_xor(p, 4, 32);
    p += __shfl_xor(p, 2, 32);
    p += __shfl_xor(p, 1, 32);
    return p;
}

__device__ __forceinline__ float edot(float xa, float xb, float xra, float xrb,
                                      float aa, float ab) {
    float ta = xa + xra; ta = ta > 0.f ? ta : ATT_SLOPE * ta;
    float tb = xb + xrb; tb = tb > 0.f ? tb : ATT_SLOPE * tb;
    return fmaf(ta, aa, tb * ab);
}

template <int LAYER>
__global__ __launch_bounds__(256) void gat_edge(const float* __restrict__ xl,
                                                const float* __restrict__ xr,
                                                const int* __restrict__ offsets,
                                                const int* __restrict__ csr_src,
                                                const float* __restrict__ att,
                                                const float* __restrict__ bias,
                                                const float* __restrict__ h1,
                                                float* __restrict__ outp, int nNodes) {
    int wave = (int)((blockIdx.x * blockDim.x + threadIdx.x) >> 6);
    int lane = threadIdx.x & 63;
    if (wave >= nNodes) return;
    int n = wave;
    int fo = (lane >> 5) * 64;   // head feature offset (0 or 64)
    int hl = lane & 31;          // channel within half
    int ca = fo + hl, cb = fo + hl + 32;
    float aa = att[ca], ab = att[cb];
    size_t nb = (size_t)n * HID;
    float xra = xr[nb + ca], xrb = xr[nb + cb];
    int e0 = offsets[n], e1 = offsets[n + 1];
    float m = -INFINITY, l = 0.f, acc_a = 0.f, acc_b = 0.f;
    int e = e0;
    for (; e + 4 <= e1; e += 4) {
        int s0 = csr_src[e + 0], s1 = csr_src[e + 1];
        int s2 = csr_src[e + 2], s3 = csr_src[e + 3];
        const float* r0 = xl + (size_t)s0 * HID + ca;
        const float* r1 = xl + (size_t)s1 * HID + ca;
        const float* r2 = xl + (size_t)s2 * HID + ca;
        const float* r3 = xl + (size_t)s3 * HID + ca;
        float xa0 = r0[0], xb0 = r0[32];
        float xa1 = r1[0], xb1 = r1[32];
        float xa2 = r2[0], xb2 = r2[32];
        float xa3 = r3[0], xb3 = r3[32];
        float p0 = edot(xa0, xb0, xra, xrb, aa, ab);
        float p1 = edot(xa1, xb1, xra, xrb, aa, ab);
        float p2 = edot(xa2, xb2, xra, xrb, aa, ab);
        float p3 = edot(xa3, xb3, xra, xrb, aa, ab);
        p0 = hred32(p0); p1 = hred32(p1); p2 = hred32(p2); p3 = hred32(p3);
        float nm = fmaxf(fmaxf(m, fmaxf(p0, p1)), fmaxf(p2, p3));
        float sc = __expf(m - nm);
        float w0 = __expf(p0 - nm), w1 = __expf(p1 - nm);
        float w2 = __expf(p2 - nm), w3 = __expf(p3 - nm);
        l = l * sc + ((w0 + w1) + (w2 + w3));
        acc_a = acc_a * sc + (fmaf(w0, xa0, w1 * xa1) + fmaf(w2, xa2, w3 * xa3));
        acc_b = acc_b * sc + (fmaf(w0, xb0, w1 * xb1) + fmaf(w2, xb2, w3 * xb3));
        m = nm;
    }
    for (; e < e1; ++e) {
        int s = csr_src[e];
        const float* r0 = xl + (size_t)s * HID + ca;
        float xa = r0[0], xb = r0[32];
        float p = edot(xa, xb, xra, xrb, aa, ab);
        p = hred32(p);
        float nm = fmaxf(m, p);
        float sc = __expf(m - nm);
        float w = __expf(p - nm);
        l = l * sc + w;
        acc_a = acc_a * sc + w * xa;
        acc_b = acc_b * sc + w * xb;
        m = nm;
    }
    float inv = 1.f / (l + 1e-16f);
    float oa = acc_a * inv + bias[ca];
    float ob = acc_b * inv + bias[cb];
    if (LAYER == 1) {
        oa = oa > 0.f ? oa : OUT_SLOPE * oa;
        ob = ob > 0.f ? ob : OUT_SLOPE * ob;
        outp[nb + ca] = oa;
        outp[nb + cb] = ob;
    } else {
        outp[nb + ca] = h1[nb + ca] + oa;
        outp[nb + cb] = h1[nb + cb] + ob;
    }
}

// ---------------------------------------------------------------- launch
extern "C" void kernel_launch(void* const* d_in, const int* in_sizes, int n_in,
                              void* d_out, int out_size, void* d_ws, size_t ws_size,
                              hipStream_t stream) {
    const float* x    = (const float*)d_in[0];
    const int* ei     = (const int*)d_in[1];
    const float* w_l1 = (const float*)d_in[2];
    const float* w_r1 = (const float*)d_in[3];
    const float* att1 = (const float*)d_in[4];
    const float* b1   = (const float*)d_in[5];
    const float* w_l2 = (const float*)d_in[6];
    const float* w_r2 = (const float*)d_in[7];
    const float* att2 = (const float*)d_in[8];
    const float* b2   = (const float*)d_in[9];

    const int N = in_sizes[0] / HID;
    const int E = in_sizes[1] / 2;
    const int* srcp = ei;
    const int* dstp = ei + E;

    // workspace layout: float4-aligned buffers first
    float* xlbuf  = (float*)d_ws;                    // N*128
    float* xrbuf  = xlbuf + (size_t)N * HID;         // N*128
    float* h1buf  = xrbuf + (size_t)N * HID;         // N*128
    int* deg      = (int*)(h1buf + (size_t)N * HID); // N
    int* offsets  = deg + N;                         // N+1
    int* cursor   = offsets + (N + 1);               // N
    int* csr_src  = cursor + N;                      // E
    int* bsum     = csr_src + E;                     // 64
    int* bbase    = bsum + 64;                       // 64
    float* outf   = (float*)d_out;

    const int eb = (E + 255) / 256;
    const int gb = (N + GM - 1) / GM;
    const int ab = (N + 3) / 4;
    const int ch = (N + 63) / 64;    // per-block scan chunk (<=1024 for N<=65536)

    // CSR (shared by both layers)
    hipMemsetAsync(deg, 0, (size_t)N * sizeof(int), stream);
    count_deg<<<eb, 256, 0, stream>>>(dstp, deg, E);
    scan_part<<<64, 1024, 0, stream>>>(deg, bsum, N, ch);
    scan_base<<<1, 64, 0, stream>>>(bsum, bbase, 64);
    scan_final<<<64, 1024, 0, stream>>>(deg, bbase, offsets, cursor, N, E, ch);
    fill_csr<<<eb, 256, 0, stream>>>(srcp, dstp, cursor, csr_src, E);

    // layer 1
    gemm_xlxr<<<gb, 256, 0, stream>>>(x, w_l1, w_r1, xlbuf, xrbuf, N);
    gat_edge<1><<<ab, 256, 0, stream>>>(xlbuf, xrbuf, offsets, csr_src, att1, b1,
                                        nullptr, h1buf, N);
    // layer 2
    gemm_xlxr<<<gb, 256, 0, stream>>>(h1buf, w_l2, w_r2, xlbuf, xrbuf, N);
    gat_edge<2><<<ab, 256, 0, stream>>>(xlbuf, xrbuf, offsets, csr_src, att2, b2,
                                        h1buf, outf, N);
}